// Round 19
// baseline (84.272 us; speedup 1.0000x reference)
//
#include <hip/hip_runtime.h>
#include <hip/hip_bf16.h>
#include <math.h>

// Problem constants
#define TT 2048
#define BB 2
#define DM 1024
#define NH 16
#define HD 64
#define KVD 16
#define BT (BB*TT)   // 4096 rows total
#define QP 256       // NH*KVD

typedef short short8  __attribute__((ext_vector_type(8)));
typedef short short4v __attribute__((ext_vector_type(4)));
typedef float f32x4   __attribute__((ext_vector_type(4)));
typedef float f32x16  __attribute__((ext_vector_type(16)));

static __device__ __forceinline__ short f2bf(float f) {
    union { float f; unsigned u; } v; v.f = f;
    unsigned r = v.u + 0x7fffu + ((v.u >> 16) & 1u);   // round-to-nearest-even
    return (short)(r >> 16);
}

// Native v_exp_f32 (1 TRANS instr); v_exp_f32(-inf) = 0 handles the causal mask.
static __device__ __forceinline__ float fexp2(float x) {
#if __has_builtin(__builtin_amdgcn_exp2f)
    return __builtin_amdgcn_exp2f(x);
#else
    return exp2f(x);
#endif
}

// ---------------- prep_all: absorbed weights + x->bf16 + latent kvc ----------------
__global__ __launch_bounds__(256) void prep_all(
    const float* __restrict__ Wq, const float* __restrict__ Wk,
    const float* __restrict__ bq,
    const float* __restrict__ Wv, const float* __restrict__ Wo,
    const float* __restrict__ bv,
    const float* __restrict__ x,  const float* __restrict__ Wc,
    const float* __restrict__ bc,
    short* __restrict__ Wqt, float* __restrict__ bqp,
    short* __restrict__ Wvot, float* __restrict__ bop_part,
    short* __restrict__ x_bf, short* __restrict__ kvc16, short* __restrict__ kvcT)
{
    __shared__ __align__(16) char smem[20736];
    int bid = blockIdx.x, tid = threadIdx.x;
    if (bid < 256) {
        // ---- Wqt + bqp ----
        const float SC = 0.18033688011112042f;  // log2(e)/8
        float (*wk)[64] = (float(*)[64])smem;            // 4096 B
        float (*wq)[65] = (float(*)[65])(smem + 4096);   // 16640 B
        int h = bid >> 4, dt = bid & 15;
        int d0 = dt * 64;
        for (int idx = tid; idx < 1024; idx += 256) {
            int j = idx >> 6, e = idx & 63;
            wk[j][e] = Wk[j*DM + h*HD + e];
        }
        #pragma unroll
        for (int i = 0; i < 16; ++i) {
            int idx = i*256 + tid;
            int r = idx >> 6, e = idx & 63;
            wq[r][e] = Wq[(d0 + r)*DM + h*HD + e];
        }
        __syncthreads();
        int r = tid & 63, j0 = (tid >> 6) * 4;
        float a0=0.f, a1=0.f, a2=0.f, a3=0.f;
        #pragma unroll 8
        for (int e = 0; e < 64; ++e) {
            float a = wq[r][e];
            a0 += a * wk[j0+0][e];
            a1 += a * wk[j0+1][e];
            a2 += a * wk[j0+2][e];
            a3 += a * wk[j0+3][e];
        }
        Wqt[(h*16 + j0+0)*DM + d0 + r] = f2bf(a0 * SC);
        Wqt[(h*16 + j0+1)*DM + d0 + r] = f2bf(a1 * SC);
        Wqt[(h*16 + j0+2)*DM + d0 + r] = f2bf(a2 * SC);
        Wqt[(h*16 + j0+3)*DM + d0 + r] = f2bf(a3 * SC);
        if (dt == 0 && tid < 16) {
            int j = tid;
            float acc = 0.f;
            #pragma unroll 8
            for (int e = 0; e < 64; ++e) acc += bq[h*HD + e] * wk[j][e];
            bqp[h*16 + j] = acc * SC;
        }
    } else if (bid < 320) {
        // ---- Wvot + bop_part ----
        float (*wv)[64] = (float(*)[64])smem;            // 4096 B
        float* bvs = (float*)(smem + 4096);              // 256 B
        int hb = bid - 256;
        int h = hb >> 2, nt = hb & 3;
        int n = nt*256 + tid;
        for (int idx = tid; idx < 1024; idx += 256) {
            int j = idx >> 6, e = idx & 63;
            wv[j][e] = Wv[j*DM + h*HD + e];
        }
        if (tid < 64) bvs[tid] = bv[h*HD + tid];
        __syncthreads();
        float acc[16];
        #pragma unroll
        for (int j = 0; j < 16; ++j) acc[j] = 0.f;
        float bacc = 0.f;
        #pragma unroll 4
        for (int e = 0; e < 64; ++e) {
            float wo = Wo[(h*HD + e)*DM + n];
            bacc += bvs[e] * wo;
            #pragma unroll
            for (int j = 0; j < 16; ++j) acc[j] += wv[j][e] * wo;
        }
        short8 o0, o1;
        #pragma unroll
        for (int j = 0; j < 8; ++j) { o0[j] = f2bf(acc[j]); o1[j] = f2bf(acc[j+8]); }
        *(short8*)(Wvot + n*QP + h*16)     = o0;
        *(short8*)(Wvot + n*QP + h*16 + 8) = o1;
        bop_part[h*DM + n] = bacc;
    } else {
        // ---- x -> bf16, kvc ----
        float (*xs)[DM]      = (float(*)[DM])smem;               // 16384 B
        float (*part)[16][17] = (float(*)[16][17])(smem + 16384); // 4352 B
        int t0 = (bid - 320) * 4;
        #pragma unroll
        for (int i = 0; i < 4; ++i) {
            float4 xv = *(const float4*)(x + (t0+i)*DM + tid*4);
            *(float4*)(&xs[i][tid*4]) = xv;
            short4v xb;
            xb[0]=f2bf(xv.x); xb[1]=f2bf(xv.y); xb[2]=f2bf(xv.z); xb[3]=f2bf(xv.w);
            *(short4v*)(x_bf + (t0+i)*DM + tid*4) = xb;
        }
        __syncthreads();
        int g = tid >> 4, n = tid & 15;
        float a0=0.f, a1=0.f, a2=0.f, a3=0.f;
        #pragma unroll 4
        for (int k = 0; k < 64; ++k) {
            float wc = Wc[(g*64 + k)*KVD + n];
            a0 += xs[0][g*64+k]*wc; a1 += xs[1][g*64+k]*wc;
            a2 += xs[2][g*64+k]*wc; a3 += xs[3][g*64+k]*wc;
        }
        part[0][g][n]=a0; part[1][g][n]=a1; part[2][g][n]=a2; part[3][g][n]=a3;
        __syncthreads();
        if (tid < 64) {
            int i = tid >> 4, nn = tid & 15;
            float s = bc[nn];
            #pragma unroll
            for (int gg = 0; gg < 16; ++gg) s += part[i][gg][nn];
            short v = f2bf(s);
            int t = t0 + i;
            kvc16[t*16 + nn] = v;
            int b = t >> 11, tl = t & (TT-1);
            // tiled V: tile kt = tl>>5, local kv = tl&31 -> half, kv16
            int kt = tl >> 5, kvl = tl & 31;
            int half = kvl >> 4, k16 = kvl & 15;
            int base = ((b*64 + kt)*2 + half) * 512;   // shorts: half-tile = 32x16
            kvcT[base + nn*16 + k16]        = v;
            kvcT[base + (16+nn)*16 + k16]   = (nn == 0) ? (short)0x3F80 : (short)0;
        }
    }
}

// ---------------- q' GEMM: q16t = (x @ Wq' + bq') in B-frag-tiled layout ----------------
// q16t[(b*64+qt)*16 + h][q(32)][lat(16)]: the attn KV kernel's Q-fragment for
// (b,h,qt) is then ONE dense 16B load per lane (j=q=l31, k=lat=8hi+e).
__global__ __launch_bounds__(256) void qgemm(
    const short* __restrict__ x_bf, const short* __restrict__ Wqt,
    const float* __restrict__ bqp, short* __restrict__ q16t)
{
    int bid = blockIdx.x;
    int w = threadIdx.x >> 6, lane = threadIdx.x & 63;
    int l15 = lane & 15, g = lane >> 4;
    int m0 = (bid >> 4)*64 + w*16;
    int nb = (bid & 15)*16;
    f32x4 acc = {0.f,0.f,0.f,0.f};
    const short* arow = x_bf + (m0 + l15)*DM + 8*g;
    const short* brow = Wqt  + (nb + l15)*DM + 8*g;
    for (int k0 = 0; k0 < DM; k0 += 32) {
        short8 a = *(const short8*)(arow + k0);
        short8 b = *(const short8*)(brow + k0);
        acc = __builtin_amdgcn_mfma_f32_16x16x32_bf16(a, b, acc, 0, 0, 0);
    }
    int c = nb + l15;
    int h = c >> 4, lat = c & 15;
    float bias = bqp[c];
    #pragma unroll
    for (int r = 0; r < 4; ++r) {
        int row = m0 + 4*g + r;
        int b_ = row >> 11, t = row & (TT-1);
        int qt = t >> 5, q = t & 31;
        q16t[(((b_*64 + qt)*16 + h) << 9) + q*16 + lat] = f2bf(acc[r] + bias);
    }
}

// ---------------- causal latent attention (KV loop only) ----------------
// Block = one (b,h,{pp, 63-pp}) pair -> 65 KV-tiles/block (uniform); 1024 blocks.
// XCD-locality decode keeps h-siblings of a (b,pp) on one XCD (FETCH 8MB).
// Q-fragments are single 16B loads from q16t (B-frag-tiled). Loop body is
// round-18's: 2 tiles/iteration, dual accumulators, next-group prefetch,
// s_setprio around MFMA clusters, denom FREE from PV col 16 (ones-row).
__global__ __launch_bounds__(256, 4) void attn(
    const short* __restrict__ q16t,
    const short* __restrict__ kvc16, const short* __restrict__ kvcT,
    short* __restrict__ u_bf)
{
    int bid = blockIdx.x;
    int chunk = bid >> 7;                 // 0..7
    int h  = (bid >> 3) & 15;
    int bp = chunk * 8 + (bid & 7);       // 0..63
    int b  = bp >> 5, pp = bp & 31;       // pp in [0,32)
    int tid = threadIdx.x;
    int w = tid >> 6, lane = tid & 63;
    int l31 = lane & 31, hi = lane >> 5;

    __shared__ __align__(16) float ulds[4][32][17];   // 8704 B

    const short* kbase = kvc16 + (b*TT + l31)*16 + 8*hi;
    const short* vbase = kvcT + b*65536 + l31*16 + 8*hi;   // + kt*1024 (+512 for vb)
    const short* qb_t  = q16t + ((b*64) << 13>> 4)*0 + (((b*64)*16 + h) << 9) + l31*16 + 8*hi;
    // per-qt stride in shorts: 16 h-tiles * 512 = 8192

    #pragma unroll 1
    for (int it = 0; it < 2; ++it) {
        int qt = it ? (63 - pp) : pp;
        int qbase = qt * 32;
        short8 qf = *(const short8*)(qb_t + qt*8192);   // B-frag: j=q=l31, k=lat

        int ntiles = qt + 1;
        int t0 = (w * ntiles) >> 2;
        int t1 = ((w + 1) * ntiles) >> 2;

        f32x16 u0, u1, zf;
        #pragma unroll
        for (int r = 0; r < 16; ++r) { u0[r] = 0.f; u1[r] = 0.f; zf[r] = 0.f; }

        int kt = t0;
        if (kt + 2 <= t1) {
            // initial loads for the first 2-tile group
            short8 kf0 = *(const short8*)(kbase + (kt << 9));
            short8 kf1 = *(const short8*)(kbase + ((kt + 1) << 9));
            const short* v0 = vbase + (kt << 10);
            short8 va0 = *(const short8*)(v0);
            short8 vb0 = *(const short8*)(v0 + 512);
            short8 va1 = *(const short8*)(v0 + 1024);
            short8 vb1 = *(const short8*)(v0 + 1536);
            #pragma unroll 2
            for (; kt + 2 <= t1; kt += 2) {
                __builtin_amdgcn_s_setprio(1);
                f32x16 st0 = __builtin_amdgcn_mfma_f32_32x32x16_bf16(kf0, qf, zf, 0, 0, 0);
                f32x16 st1 = __builtin_amdgcn_mfma_f32_32x32x16_bf16(kf1, qf, zf, 0, 0, 0);
                __builtin_amdgcn_s_setprio(0);
                // prefetch next 2-tile group under the exp/pack chain
                short8 kf0n = kf0, kf1n = kf1, va0n = va0, vb0n = vb0, va1n = va1, vb1n = vb1;
                if (kt + 4 <= t1) {
                    const short* vn = vbase + ((kt + 2) << 10);
                    kf0n = *(const short8*)(kbase + ((kt + 2) << 9));
                    kf1n = *(const short8*)(kbase + ((kt + 3) << 9));
                    va0n = *(const short8*)(vn);
                    vb0n = *(const short8*)(vn + 512);
                    va1n = *(const short8*)(vn + 1024);
                    vb1n = *(const short8*)(vn + 1536);
                }
                if (kt + 1 == qt) {                  // diagonal can only be the last tile
                    #pragma unroll
                    for (int r = 0; r < 16; ++r) {
                        int kvl = (r & 3) + 8*(r >> 2) + 4*hi;
                        if (kvl > l31) st1[r] = -INFINITY;
                    }
                }
                int wd[16];
                #pragma unroll
                for (int i = 0; i < 8; ++i) {        // exp fused into pack pairs
                    float pa = fexp2(st0[2*i]), pb = fexp2(st0[2*i+1]);
                    asm("v_cvt_pk_bf16_f32 %0, %1, %2" : "=v"(wd[i]) : "v"(pa), "v"(pb));
                    float pc = fexp2(st1[2*i]), pd = fexp2(st1[2*i+1]);
                    asm("v_cvt_pk_bf16_f32 %0, %1, %2" : "=v"(wd[8+i]) : "v"(pc), "v"(pd));
                }
                int c00 = wd[0],  c02 = wd[2],  c01 = wd[1],  c03 = wd[3];
                int c10 = wd[4],  c12 = wd[6],  c11 = wd[5],  c13 = wd[7];
                int d00 = wd[8],  d02 = wd[10], d01 = wd[9],  d03 = wd[11];
                int d10 = wd[12], d12 = wd[14], d11 = wd[13], d13 = wd[15];
                asm volatile("v_permlane32_swap_b32 %0, %1" : "+v"(c00), "+v"(c02));
                asm volatile("v_permlane32_swap_b32 %0, %1" : "+v"(c01), "+v"(c03));
                asm volatile("v_permlane32_swap_b32 %0, %1" : "+v"(c10), "+v"(c12));
                asm volatile("v_permlane32_swap_b32 %0, %1" : "+v"(c11), "+v"(c13));
                asm volatile("v_permlane32_swap_b32 %0, %1" : "+v"(d00), "+v"(d02));
                asm volatile("v_permlane32_swap_b32 %0, %1" : "+v"(d01), "+v"(d03));
                asm volatile("v_permlane32_swap_b32 %0, %1" : "+v"(d10), "+v"(d12));
                asm volatile("v_permlane32_swap_b32 %0, %1" : "+v"(d11), "+v"(d13));
                union { int i4[4]; short8 s8; } pa0, pa1, pb0, pb1;
                pa0.i4[0]=c00; pa0.i4[1]=c01; pa0.i4[2]=c02; pa0.i4[3]=c03;
                pa1.i4[0]=c10; pa1.i4[1]=c11; pa1.i4[2]=c12; pa1.i4[3]=c13;
                pb0.i4[0]=d00; pb0.i4[1]=d01; pb0.i4[2]=d02; pb0.i4[3]=d03;
                pb1.i4[0]=d10; pb1.i4[1]=d11; pb1.i4[2]=d12; pb1.i4[3]=d13;
                __builtin_amdgcn_s_setprio(1);
                u0 = __builtin_amdgcn_mfma_f32_32x32x16_bf16(pa0.s8, va0, u0, 0, 0, 0);
                u1 = __builtin_amdgcn_mfma_f32_32x32x16_bf16(pb0.s8, va1, u1, 0, 0, 0);
                u0 = __builtin_amdgcn_mfma_f32_32x32x16_bf16(pa1.s8, vb0, u0, 0, 0, 0);
                u1 = __builtin_amdgcn_mfma_f32_32x32x16_bf16(pb1.s8, vb1, u1, 0, 0, 0);
                __builtin_amdgcn_s_setprio(0);
                kf0 = kf0n; kf1 = kf1n;
                va0 = va0n; vb0 = vb0n; va1 = va1n; vb1 = vb1n;
            }
        }
        // ---- tail: single tile (possibly diagonal) ----
        if (kt < t1) {
            short8 kf = *(const short8*)(kbase + (kt << 9));
            const short* v0 = vbase + (kt << 10);
            short8 va = *(const short8*)(v0);
            short8 vb = *(const short8*)(v0 + 512);
            f32x16 st = __builtin_amdgcn_mfma_f32_32x32x16_bf16(kf, qf, zf, 0, 0, 0);
            if (kt == qt) {
                #pragma unroll
                for (int r = 0; r < 16; ++r) {
                    int kvl = (r & 3) + 8*(r >> 2) + 4*hi;
                    if (kvl > l31) st[r] = -INFINITY;
                }
            }
            int wd[8];
            #pragma unroll
            for (int i = 0; i < 8; ++i) {
                float pa = fexp2(st[2*i]), pb = fexp2(st[2*i+1]);
                asm("v_cvt_pk_bf16_f32 %0, %1, %2" : "=v"(wd[i]) : "v"(pa), "v"(pb));
            }
            int c00 = wd[0], c02 = wd[2], c01 = wd[1], c03 = wd[3];
            int c10 = wd[4], c12 = wd[6], c11 = wd[5], c13 = wd[7];
            asm volatile("v_permlane32_swap_b32 %0, %1" : "+v"(c00), "+v"(c02));
            asm volatile("v_permlane32_swap_b32 %0, %1" : "+v"(c01), "+v"(c03));
            asm volatile("v_permlane32_swap_b32 %0, %1" : "+v"(c10), "+v"(c12));
            asm volatile("v_permlane32_swap_b32 %0, %1" : "+v"(c11), "+v"(c13));
            union { int i4[4]; short8 s8; } pa0, pa1;
            pa0.i4[0]=c00; pa0.i4[1]=c01; pa0.i4[2]=c02; pa0.i4[3]=c03;
            pa1.i4[0]=c10; pa1.i4[1]=c11; pa1.i4[2]=c12; pa1.i4[3]=c13;
            u0 = __builtin_amdgcn_mfma_f32_32x32x16_bf16(pa0.s8, va, u0, 0, 0, 0);
            u0 = __builtin_amdgcn_mfma_f32_32x32x16_bf16(pa1.s8, vb, u0, 0, 0, 0);
        }
        #pragma unroll
        for (int r = 0; r < 16; ++r) u0[r] += u1[r];

        // ---- combine (partials additive; col 16 = denominator) ----
        #pragma unroll
        for (int r = 0; r < 16; ++r) {
            int q = (r & 3) + 8*(r >> 2) + 4*hi;
            if (l31 < 17) ulds[w][q][l31] = u0[r];
        }
        __syncthreads();
        #pragma unroll
        for (int e = 0; e < 2; ++e) {
            int idx = tid*2 + e;
            int q = idx >> 4, lat = idx & 15;
            float us = ulds[0][q][lat] + ulds[1][q][lat] + ulds[2][q][lat] + ulds[3][q][lat];
            float dd = ulds[0][q][16]  + ulds[1][q][16]  + ulds[2][q][16]  + ulds[3][q][16];
            u_bf[(b*TT + qbase + q)*QP + h*16 + lat] = f2bf(us / dd);
        }
        __syncthreads();   // ulds reuse safety before next it
    }
}

// ---------------- output GEMM: out = U @ Wvo + (bo + bv@Wo) ----------------
__global__ __launch_bounds__(256) void ogemm(
    const short* __restrict__ u_bf, const short* __restrict__ Wvot,
    const float* __restrict__ bo, const float* __restrict__ bop_part,
    float* __restrict__ out)
{
    int bid = blockIdx.x;
    int w = threadIdx.x >> 6, lane = threadIdx.x & 63;
    int l15 = lane & 15, g = lane >> 4;
    int m0 = (bid >> 4)*64 + w*16;
    int nb = (bid & 15)*64;
    __shared__ float bs[64];
    int tid = threadIdx.x;
    if (tid < 64) {
        int n = nb + tid;
        float s = bo[n];
        #pragma unroll
        for (int hh = 0; hh < 16; ++hh) s += bop_part[hh*DM + n];
        bs[tid] = s;
    }
    __syncthreads();
    f32x4 acc[4];
    #pragma unroll
    for (int nt = 0; nt < 4; ++nt) acc[nt] = (f32x4){0.f,0.f,0.f,0.f};
    const short* arow = u_bf + (m0 + l15)*QP + 8*g;
    for (int k0 = 0; k0 < QP; k0 += 32) {
        short8 a = *(const short8*)(arow + k0);
        #pragma unroll
        for (int nt = 0; nt < 4; ++nt) {
            short8 bfr = *(const short8*)(Wvot + (nb + nt*16 + l15)*QP + k0 + 8*g);
            acc[nt] = __builtin_amdgcn_mfma_f32_16x16x32_bf16(a, bfr, acc[nt], 0, 0, 0);
        }
    }
    #pragma unroll
    for (int nt = 0; nt < 4; ++nt) {
        int n = nb + nt*16 + l15;
        float bias = bs[nt*16 + l15];
        #pragma unroll
        for (int r = 0; r < 4; ++r)
            out[(m0 + 4*g + r)*DM + n] = acc[nt][r] + bias;
    }
}

extern "C" void kernel_launch(void* const* d_in, const int* in_sizes, int n_in,
                              void* d_out, int out_size, void* d_ws, size_t ws_size,
                              hipStream_t stream) {
    const float* x  = (const float*)d_in[0];
    const float* Wc = (const float*)d_in[1];
    const float* bc = (const float*)d_in[2];
    const float* Wk = (const float*)d_in[3];
    // d_in[4] = bk: drops out of softmax (constant per row)
    const float* Wv = (const float*)d_in[5];
    const float* bv = (const float*)d_in[6];
    const float* Wq = (const float*)d_in[7];
    const float* bq = (const float*)d_in[8];
    const float* Wo = (const float*)d_in[9];
    const float* bo = (const float*)d_in[10];
    // d_in[11] = mask: causal, implemented directly
    float* out = (float*)d_out;

    char* ws = (char*)d_ws;                       // needs 16 MiB
    short* x_bf     = (short*)(ws);                              // 8 MiB
    short* Wqt      = (short*)(ws + (8u<<20));                   // 512 KiB
    short* Wvot     = (short*)(ws + (8u<<20) + (512u<<10));      // 512 KiB
    float* bqp      = (float*)(ws + (9u<<20));                   // 1 KiB
    float* bop_part = (float*)(ws + (9u<<20) + 8192);            // 64 KiB
    short* kvc16    = (short*)(ws + (9u<<20) + (512u<<10));      // 128 KiB
    short* kvcT     = (short*)(ws + (9u<<20) + (768u<<10));      // 256 KiB tiled [b][kt][half][32][16]
    short* q16t     = (short*)(ws + (10u<<20));                  // 2 MiB tiled [(b*64+qt)*16+h][32][16]
    short* u_bf     = (short*)(ws + (14u<<20));                  // 2 MiB

    hipLaunchKernelGGL(prep_all, dim3(1344), dim3(256), 0, stream,
                       Wq, Wk, bq, Wv, Wo, bv, x, Wc, bc,
                       Wqt, bqp, Wvot, bop_part, x_bf, kvc16, kvcT);
    hipLaunchKernelGGL(qgemm,    dim3(1024), dim3(256), 0, stream,
                       x_bf, Wqt, bqp, q16t);
    hipLaunchKernelGGL(attn,     dim3(1024), dim3(256), 0, stream,
                       q16t, kvc16, kvcT, u_bf);
    hipLaunchKernelGGL(ogemm,    dim3(1024), dim3(256), 0, stream,
                       u_bf, Wvot, bo, bop_part, out);
}

// Round 20
// 81.190 us; speedup vs baseline: 1.0380x; 1.0380x over previous
//
#include <hip/hip_runtime.h>
#include <hip/hip_bf16.h>
#include <math.h>

// Problem constants
#define TT 2048
#define BB 2
#define DM 1024
#define NH 16
#define HD 64
#define KVD 16
#define BT (BB*TT)   // 4096 rows total
#define QP 256       // NH*KVD

typedef short short8  __attribute__((ext_vector_type(8)));
typedef short short4v __attribute__((ext_vector_type(4)));
typedef float f32x4   __attribute__((ext_vector_type(4)));
typedef float f32x16  __attribute__((ext_vector_type(16)));

static __device__ __forceinline__ short f2bf(float f) {
    union { float f; unsigned u; } v; v.f = f;
    unsigned r = v.u + 0x7fffu + ((v.u >> 16) & 1u);   // round-to-nearest-even
    return (short)(r >> 16);
}

// Native v_exp_f32 (1 TRANS instr); v_exp_f32(-inf) = 0 handles the causal mask.
static __device__ __forceinline__ float fexp2(float x) {
#if __has_builtin(__builtin_amdgcn_exp2f)
    return __builtin_amdgcn_exp2f(x);
#else
    return exp2f(x);
#endif
}

// ---------------- prep_all: absorbed weights + x->bf16 + latent kvc ----------------
// bid [0,256):    Wqt[c][d] = bf16(log2e/8 * Wq[d,h*64:]·Wk[j,h*64:]), c=h*16+j; bqp
// bid [256,320):  Wvot[n][h*16+j] = bf16(Wv[j,h*64:]·Wo[h*64:,n]); bop_part[h][n]
// bid [320,1344): x -> bf16; kvc16[t][16] = x[t]@Wc + bc;
//                 kvcT TILED: [b][kt(64)][half(2)][lat(32)][kv16] — each half-tile is a
//                 dense 1KB B-operand block (lat row 16 = bf16 1.0 ones-row -> PV col 16
//                 = softmax denom; rows 17..31 zero).
__global__ __launch_bounds__(256) void prep_all(
    const float* __restrict__ Wq, const float* __restrict__ Wk,
    const float* __restrict__ bq,
    const float* __restrict__ Wv, const float* __restrict__ Wo,
    const float* __restrict__ bv,
    const float* __restrict__ x,  const float* __restrict__ Wc,
    const float* __restrict__ bc,
    short* __restrict__ Wqt, float* __restrict__ bqp,
    short* __restrict__ Wvot, float* __restrict__ bop_part,
    short* __restrict__ x_bf, short* __restrict__ kvc16, short* __restrict__ kvcT)
{
    __shared__ __align__(16) char smem[20736];
    int bid = blockIdx.x, tid = threadIdx.x;
    if (bid < 256) {
        // ---- Wqt + bqp ----
        const float SC = 0.18033688011112042f;  // log2(e)/8
        float (*wk)[64] = (float(*)[64])smem;            // 4096 B
        float (*wq)[65] = (float(*)[65])(smem + 4096);   // 16640 B
        int h = bid >> 4, dt = bid & 15;
        int d0 = dt * 64;
        for (int idx = tid; idx < 1024; idx += 256) {
            int j = idx >> 6, e = idx & 63;
            wk[j][e] = Wk[j*DM + h*HD + e];
        }
        #pragma unroll
        for (int i = 0; i < 16; ++i) {
            int idx = i*256 + tid;
            int r = idx >> 6, e = idx & 63;
            wq[r][e] = Wq[(d0 + r)*DM + h*HD + e];
        }
        __syncthreads();
        int r = tid & 63, j0 = (tid >> 6) * 4;
        float a0=0.f, a1=0.f, a2=0.f, a3=0.f;
        #pragma unroll 8
        for (int e = 0; e < 64; ++e) {
            float a = wq[r][e];
            a0 += a * wk[j0+0][e];
            a1 += a * wk[j0+1][e];
            a2 += a * wk[j0+2][e];
            a3 += a * wk[j0+3][e];
        }
        Wqt[(h*16 + j0+0)*DM + d0 + r] = f2bf(a0 * SC);
        Wqt[(h*16 + j0+1)*DM + d0 + r] = f2bf(a1 * SC);
        Wqt[(h*16 + j0+2)*DM + d0 + r] = f2bf(a2 * SC);
        Wqt[(h*16 + j0+3)*DM + d0 + r] = f2bf(a3 * SC);
        if (dt == 0 && tid < 16) {
            int j = tid;
            float acc = 0.f;
            #pragma unroll 8
            for (int e = 0; e < 64; ++e) acc += bq[h*HD + e] * wk[j][e];
            bqp[h*16 + j] = acc * SC;
        }
    } else if (bid < 320) {
        // ---- Wvot + bop_part ----
        float (*wv)[64] = (float(*)[64])smem;            // 4096 B
        float* bvs = (float*)(smem + 4096);              // 256 B
        int hb = bid - 256;
        int h = hb >> 2, nt = hb & 3;
        int n = nt*256 + tid;
        for (int idx = tid; idx < 1024; idx += 256) {
            int j = idx >> 6, e = idx & 63;
            wv[j][e] = Wv[j*DM + h*HD + e];
        }
        if (tid < 64) bvs[tid] = bv[h*HD + tid];
        __syncthreads();
        float acc[16];
        #pragma unroll
        for (int j = 0; j < 16; ++j) acc[j] = 0.f;
        float bacc = 0.f;
        #pragma unroll 4
        for (int e = 0; e < 64; ++e) {
            float wo = Wo[(h*HD + e)*DM + n];
            bacc += bvs[e] * wo;
            #pragma unroll
            for (int j = 0; j < 16; ++j) acc[j] += wv[j][e] * wo;
        }
        short8 o0, o1;
        #pragma unroll
        for (int j = 0; j < 8; ++j) { o0[j] = f2bf(acc[j]); o1[j] = f2bf(acc[j+8]); }
        *(short8*)(Wvot + n*QP + h*16)     = o0;
        *(short8*)(Wvot + n*QP + h*16 + 8) = o1;
        bop_part[h*DM + n] = bacc;
    } else {
        // ---- x -> bf16, kvc ----
        float (*xs)[DM]      = (float(*)[DM])smem;               // 16384 B
        float (*part)[16][17] = (float(*)[16][17])(smem + 16384); // 4352 B
        int t0 = (bid - 320) * 4;
        #pragma unroll
        for (int i = 0; i < 4; ++i) {
            float4 xv = *(const float4*)(x + (t0+i)*DM + tid*4);
            *(float4*)(&xs[i][tid*4]) = xv;
            short4v xb;
            xb[0]=f2bf(xv.x); xb[1]=f2bf(xv.y); xb[2]=f2bf(xv.z); xb[3]=f2bf(xv.w);
            *(short4v*)(x_bf + (t0+i)*DM + tid*4) = xb;
        }
        __syncthreads();
        int g = tid >> 4, n = tid & 15;
        float a0=0.f, a1=0.f, a2=0.f, a3=0.f;
        #pragma unroll 4
        for (int k = 0; k < 64; ++k) {
            float wc = Wc[(g*64 + k)*KVD + n];
            a0 += xs[0][g*64+k]*wc; a1 += xs[1][g*64+k]*wc;
            a2 += xs[2][g*64+k]*wc; a3 += xs[3][g*64+k]*wc;
        }
        part[0][g][n]=a0; part[1][g][n]=a1; part[2][g][n]=a2; part[3][g][n]=a3;
        __syncthreads();
        if (tid < 64) {
            int i = tid >> 4, nn = tid & 15;
            float s = bc[nn];
            #pragma unroll
            for (int gg = 0; gg < 16; ++gg) s += part[i][gg][nn];
            short v = f2bf(s);
            int t = t0 + i;
            kvc16[t*16 + nn] = v;
            int b = t >> 11, tl = t & (TT-1);
            // tiled V: tile kt = tl>>5, local kv = tl&31 -> half, kv16
            int kt = tl >> 5, kvl = tl & 31;
            int half = kvl >> 4, k16 = kvl & 15;
            int base = ((b*64 + kt)*2 + half) * 512;   // shorts: half-tile = 32x16
            kvcT[base + nn*16 + k16]        = v;
            kvcT[base + (16+nn)*16 + k16]   = (nn == 0) ? (short)0x3F80 : (short)0;
        }
    }
}

// ---------------- fused q'-GEMM + causal latent attention ----------------
// Block = one (b,h,{pp, 63-pp}) pair -> 65 KV-tiles/block (uniform); 1024 blocks
// = 4 blocks/CU; launch_bounds(256,4) -> VGPR cap 128.
// Stage A: 4 waves compute the 64x16 q' pair-tile over full K (32 MFMAs each).
// Stage B (per qt): STRIDE-4 KV INTERLEAVE — wave w owns kt in {w, w+4, ...}:
// the block's 4 waves (on 4 SIMDs sharing one CU L1) stream the SAME 12KB K/V
// neighborhood concurrently, so ~3 of 4 tile loads hit L1 instead of L2.
// 2 tiles/iteration (kt, kt+4) with dual accumulators; exp fused into cvt_pk;
// denom FREE from PV col 16 (ones-row). Stage C: additive combine via ulds.
__global__ __launch_bounds__(256, 4) void attn(
    const short* __restrict__ x_bf, const short* __restrict__ Wqt,
    const float* __restrict__ bqp,
    const short* __restrict__ kvc16, const short* __restrict__ kvcT,
    short* __restrict__ u_bf)
{
    int bid = blockIdx.x;
    int pp = bid >> 5, bh = bid & 31;     // pp in [0,32)
    int b = bh >> 4, h = bh & 15;
    int tid = threadIdx.x;
    int w = tid >> 6, lane = tid & 63;
    int l15 = lane & 15, g = lane >> 4;
    int l31 = lane & 31, hi = lane >> 5;

    __shared__ __align__(16) char smem[10752];
    short (*qtile)[16]    = (short(*)[16])smem;              // 2048 B [64][16]
    float (*ulds)[32][17] = (float(*)[32][17])(smem + 2048); // 8704 B

    // ---- stage A: wave w computes rows [w*16, w*16+16) of the 64-row pair ----
    {
        int itile = w >> 1, half = w & 1;
        int qb = (itile ? (63 - pp) : pp) * 32 + half * 16;
        f32x4 qa = {0.f,0.f,0.f,0.f};
        const short* ar = x_bf + (b*TT + qb + l15)*DM + 8*g;
        const short* br = Wqt  + (h*16 + l15)*DM + 8*g;
        #pragma unroll 4
        for (int k0 = 0; k0 < DM; k0 += 32) {
            short8 a  = *(const short8*)(ar + k0);
            short8 bb = *(const short8*)(br + k0);
            qa = __builtin_amdgcn_mfma_f32_16x16x32_bf16(a, bb, qa, 0, 0, 0);
        }
        float bias = bqp[h*16 + l15];
        #pragma unroll
        for (int r = 0; r < 4; ++r)
            qtile[w*16 + 4*g + r][l15] = f2bf(qa[r] + bias);   // row=q, col=lat
    }
    __syncthreads();

    const short* kbase = kvc16 + (b*TT + l31)*16 + 8*hi;
    const short* vbase = kvcT + b*65536 + l31*16 + 8*hi;   // + kt*1024 (+512 for vb)

    #pragma unroll 1
    for (int it = 0; it < 2; ++it) {
        int qt = it ? (63 - pp) : pp;
        int qbase = qt * 32;
        short8 qf = *(const short8*)(&qtile[it*32 + l31][8*hi]);   // B-frag: j=q, k=lat

        f32x16 u0, u1, zf;
        #pragma unroll
        for (int r = 0; r < 16; ++r) { u0[r] = 0.f; u1[r] = 0.f; zf[r] = 0.f; }

        int kt = w;
        // ---- 2 tiles (kt, kt+4) per iteration: dual accumulators, L1 co-reuse ----
        for (; kt + 4 <= qt; kt += 8) {
            short8 kf0 = *(const short8*)(kbase + (kt << 9));
            short8 kf1 = *(const short8*)(kbase + ((kt + 4) << 9));
            const short* v0 = vbase + (kt << 10);
            const short* v1 = vbase + ((kt + 4) << 10);
            short8 va0 = *(const short8*)(v0);
            short8 vb0 = *(const short8*)(v0 + 512);
            short8 va1 = *(const short8*)(v1);
            short8 vb1 = *(const short8*)(v1 + 512);
            f32x16 st0 = __builtin_amdgcn_mfma_f32_32x32x16_bf16(kf0, qf, zf, 0, 0, 0);
            f32x16 st1 = __builtin_amdgcn_mfma_f32_32x32x16_bf16(kf1, qf, zf, 0, 0, 0);
            if (kt + 4 == qt) {                  // diagonal can only be the 2nd tile
                #pragma unroll
                for (int r = 0; r < 16; ++r) {
                    int kvl = (r & 3) + 8*(r >> 2) + 4*hi;
                    if (kvl > l31) st1[r] = -INFINITY;
                }
            }
            int wd[16];
            #pragma unroll
            for (int i = 0; i < 8; ++i) {        // exp fused into pack pairs
                float pa = fexp2(st0[2*i]), pb = fexp2(st0[2*i+1]);
                asm("v_cvt_pk_bf16_f32 %0, %1, %2" : "=v"(wd[i]) : "v"(pa), "v"(pb));
                float pc = fexp2(st1[2*i]), pd = fexp2(st1[2*i+1]);
                asm("v_cvt_pk_bf16_f32 %0, %1, %2" : "=v"(wd[8+i]) : "v"(pc), "v"(pd));
            }
            int c00 = wd[0],  c02 = wd[2],  c01 = wd[1],  c03 = wd[3];
            int c10 = wd[4],  c12 = wd[6],  c11 = wd[5],  c13 = wd[7];
            int d00 = wd[8],  d02 = wd[10], d01 = wd[9],  d03 = wd[11];
            int d10 = wd[12], d12 = wd[14], d11 = wd[13], d13 = wd[15];
            asm volatile("v_permlane32_swap_b32 %0, %1" : "+v"(c00), "+v"(c02));
            asm volatile("v_permlane32_swap_b32 %0, %1" : "+v"(c01), "+v"(c03));
            asm volatile("v_permlane32_swap_b32 %0, %1" : "+v"(c10), "+v"(c12));
            asm volatile("v_permlane32_swap_b32 %0, %1" : "+v"(c11), "+v"(c13));
            asm volatile("v_permlane32_swap_b32 %0, %1" : "+v"(d00), "+v"(d02));
            asm volatile("v_permlane32_swap_b32 %0, %1" : "+v"(d01), "+v"(d03));
            asm volatile("v_permlane32_swap_b32 %0, %1" : "+v"(d10), "+v"(d12));
            asm volatile("v_permlane32_swap_b32 %0, %1" : "+v"(d11), "+v"(d13));
            union { int i4[4]; short8 s8; } pa0, pa1, pb0, pb1;
            pa0.i4[0]=c00; pa0.i4[1]=c01; pa0.i4[2]=c02; pa0.i4[3]=c03;
            pa1.i4[0]=c10; pa1.i4[1]=c11; pa1.i4[2]=c12; pa1.i4[3]=c13;
            pb0.i4[0]=d00; pb0.i4[1]=d01; pb0.i4[2]=d02; pb0.i4[3]=d03;
            pb1.i4[0]=d10; pb1.i4[1]=d11; pb1.i4[2]=d12; pb1.i4[3]=d13;
            u0 = __builtin_amdgcn_mfma_f32_32x32x16_bf16(pa0.s8, va0, u0, 0, 0, 0);
            u1 = __builtin_amdgcn_mfma_f32_32x32x16_bf16(pb0.s8, va1, u1, 0, 0, 0);
            u0 = __builtin_amdgcn_mfma_f32_32x32x16_bf16(pa1.s8, vb0, u0, 0, 0, 0);
            u1 = __builtin_amdgcn_mfma_f32_32x32x16_bf16(pb1.s8, vb1, u1, 0, 0, 0);
        }
        // ---- tail: single tile (possibly diagonal) ----
        if (kt <= qt) {
            short8 kf = *(const short8*)(kbase + (kt << 9));
            const short* v0 = vbase + (kt << 10);
            short8 va = *(const short8*)(v0);
            short8 vb = *(const short8*)(v0 + 512);
            f32x16 st = __builtin_amdgcn_mfma_f32_32x32x16_bf16(kf, qf, zf, 0, 0, 0);
            if (kt == qt) {
                #pragma unroll
                for (int r = 0; r < 16; ++r) {
                    int kvl = (r & 3) + 8*(r >> 2) + 4*hi;
                    if (kvl > l31) st[r] = -INFINITY;
                }
            }
            int wd[8];
            #pragma unroll
            for (int i = 0; i < 8; ++i) {
                float pa = fexp2(st[2*i]), pb = fexp2(st[2*i+1]);
                asm("v_cvt_pk_bf16_f32 %0, %1, %2" : "=v"(wd[i]) : "v"(pa), "v"(pb));
            }
            int c00 = wd[0], c02 = wd[2], c01 = wd[1], c03 = wd[3];
            int c10 = wd[4], c12 = wd[6], c11 = wd[5], c13 = wd[7];
            asm volatile("v_permlane32_swap_b32 %0, %1" : "+v"(c00), "+v"(c02));
            asm volatile("v_permlane32_swap_b32 %0, %1" : "+v"(c01), "+v"(c03));
            asm volatile("v_permlane32_swap_b32 %0, %1" : "+v"(c10), "+v"(c12));
            asm volatile("v_permlane32_swap_b32 %0, %1" : "+v"(c11), "+v"(c13));
            union { int i4[4]; short8 s8; } pa0, pa1;
            pa0.i4[0]=c00; pa0.i4[1]=c01; pa0.i4[2]=c02; pa0.i4[3]=c03;
            pa1.i4[0]=c10; pa1.i4[1]=c11; pa1.i4[2]=c12; pa1.i4[3]=c13;
            u0 = __builtin_amdgcn_mfma_f32_32x32x16_bf16(pa0.s8, va, u0, 0, 0, 0);
            u0 = __builtin_amdgcn_mfma_f32_32x32x16_bf16(pa1.s8, vb, u0, 0, 0, 0);
        }
        #pragma unroll
        for (int r = 0; r < 16; ++r) u0[r] += u1[r];

        // ---- stage C: combine (partials additive; col 16 = denominator) ----
        #pragma unroll
        for (int r = 0; r < 16; ++r) {
            int q = (r & 3) + 8*(r >> 2) + 4*hi;
            if (l31 < 17) ulds[w][q][l31] = u0[r];
        }
        __syncthreads();
        #pragma unroll
        for (int e = 0; e < 2; ++e) {
            int idx = tid*2 + e;
            int q = idx >> 4, lat = idx & 15;
            float us = ulds[0][q][lat] + ulds[1][q][lat] + ulds[2][q][lat] + ulds[3][q][lat];
            float dd = ulds[0][q][16]  + ulds[1][q][16]  + ulds[2][q][16]  + ulds[3][q][16];
            u_bf[(b*TT + qbase + q)*QP + h*16 + lat] = f2bf(us / dd);
        }
        __syncthreads();   // ulds reuse safety before next it
    }
}

// ---------------- output GEMM: out = U @ Wvo + (bo + bv@Wo) ----------------
__global__ __launch_bounds__(256) void ogemm(
    const short* __restrict__ u_bf, const short* __restrict__ Wvot,
    const float* __restrict__ bo, const float* __restrict__ bop_part,
    float* __restrict__ out)
{
    int bid = blockIdx.x;
    int w = threadIdx.x >> 6, lane = threadIdx.x & 63;
    int l15 = lane & 15, g = lane >> 4;
    int m0 = (bid >> 4)*64 + w*16;
    int nb = (bid & 15)*64;
    __shared__ float bs[64];
    int tid = threadIdx.x;
    if (tid < 64) {
        int n = nb + tid;
        float s = bo[n];
        #pragma unroll
        for (int hh = 0; hh < 16; ++hh) s += bop_part[hh*DM + n];
        bs[tid] = s;
    }
    __syncthreads();
    f32x4 acc[4];
    #pragma unroll
    for (int nt = 0; nt < 4; ++nt) acc[nt] = (f32x4){0.f,0.f,0.f,0.f};
    const short* arow = u_bf + (m0 + l15)*QP + 8*g;
    for (int k0 = 0; k0 < QP; k0 += 32) {
        short8 a = *(const short8*)(arow + k0);
        #pragma unroll
        for (int nt = 0; nt < 4; ++nt) {
            short8 bfr = *(const short8*)(Wvot + (nb + nt*16 + l15)*QP + k0 + 8*g);
            acc[nt] = __builtin_amdgcn_mfma_f32_16x16x32_bf16(a, bfr, acc[nt], 0, 0, 0);
        }
    }
    #pragma unroll
    for (int nt = 0; nt < 4; ++nt) {
        int n = nb + nt*16 + l15;
        float bias = bs[nt*16 + l15];
        #pragma unroll
        for (int r = 0; r < 4; ++r)
            out[(m0 + 4*g + r)*DM + n] = acc[nt][r] + bias;
    }
}

extern "C" void kernel_launch(void* const* d_in, const int* in_sizes, int n_in,
                              void* d_out, int out_size, void* d_ws, size_t ws_size,
                              hipStream_t stream) {
    const float* x  = (const float*)d_in[0];
    const float* Wc = (const float*)d_in[1];
    const float* bc = (const float*)d_in[2];
    const float* Wk = (const float*)d_in[3];
    // d_in[4] = bk: drops out of softmax (constant per row)
    const float* Wv = (const float*)d_in[5];
    const float* bv = (const float*)d_in[6];
    const float* Wq = (const float*)d_in[7];
    const float* bq = (const float*)d_in[8];
    const float* Wo = (const float*)d_in[9];
    const float* bo = (const float*)d_in[10];
    // d_in[11] = mask: causal, implemented directly
    float* out = (float*)d_out;

    char* ws = (char*)d_ws;                       // needs 16 MiB
    short* x_bf     = (short*)(ws);                              // 8 MiB
    short* Wqt      = (short*)(ws + (8u<<20));                   // 512 KiB
    short* Wvot     = (short*)(ws + (8u<<20) + (512u<<10));      // 512 KiB
    float* bqp      = (float*)(ws + (9u<<20));                   // 1 KiB
    float* bop_part = (float*)(ws + (9u<<20) + 8192);            // 64 KiB
    short* kvc16    = (short*)(ws + (9u<<20) + (512u<<10));      // 128 KiB
    short* kvcT     = (short*)(ws + (9u<<20) + (768u<<10));      // 256 KiB tiled [b][kt][half][32][16]
    short* u_bf     = (short*)(ws + (14u<<20));                  // 2 MiB

    hipLaunchKernelGGL(prep_all, dim3(1344), dim3(256), 0, stream,
                       Wq, Wk, bq, Wv, Wo, bv, x, Wc, bc,
                       Wqt, bqp, Wvot, bop_part, x_bf, kvc16, kvcT);
    hipLaunchKernelGGL(attn,     dim3(1024), dim3(256), 0, stream,
                       x_bf, Wqt, bqp, kvc16, kvcT, u_bf);
    hipLaunchKernelGGL(ogemm,    dim3(1024), dim3(256), 0, stream,
                       u_bf, Wvot, bo, bop_part, out);
}

// Round 21
// 80.666 us; speedup vs baseline: 1.0447x; 1.0065x over previous
//
#include <hip/hip_runtime.h>
#include <hip/hip_bf16.h>
#include <math.h>

// Problem constants
#define TT 2048
#define BB 2
#define DM 1024
#define NH 16
#define HD 64
#define KVD 16
#define BT (BB*TT)   // 4096 rows total
#define QP 256       // NH*KVD

typedef short short8  __attribute__((ext_vector_type(8)));
typedef short short4v __attribute__((ext_vector_type(4)));
typedef float f32x4   __attribute__((ext_vector_type(4)));
typedef float f32x16  __attribute__((ext_vector_type(16)));

static __device__ __forceinline__ short f2bf(float f) {
    union { float f; unsigned u; } v; v.f = f;
    unsigned r = v.u + 0x7fffu + ((v.u >> 16) & 1u);   // round-to-nearest-even
    return (short)(r >> 16);
}

// Native v_exp_f32 (1 TRANS instr); v_exp_f32(-inf) = 0 handles the causal mask.
static __device__ __forceinline__ float fexp2(float x) {
#if __has_builtin(__builtin_amdgcn_exp2f)
    return __builtin_amdgcn_exp2f(x);
#else
    return exp2f(x);
#endif
}

// ---------------- prep_all: absorbed weights + x->bf16 + latent kvc ----------------
// bid [0,256):    Wqt[c][d] = bf16(log2e/8 * Wq[d,h*64:]·Wk[j,h*64:]), c=h*16+j; bqp
// bid [256,320):  Wvot[n][h*16+j] = bf16(Wv[j,h*64:]·Wo[h*64:,n]); bop_part[h][n]
// bid [320,1344): x -> bf16; kvc16[t][16] = x[t]@Wc + bc;
//                 kvcT TILED: [b][kt(64)][half(2)][lat(32)][kv16] — each half-tile is a
//                 dense 1KB B-operand block (lat row 16 = bf16 1.0 ones-row -> PV col 16
//                 = softmax denom; rows 17..31 zero).
__global__ __launch_bounds__(256) void prep_all(
    const float* __restrict__ Wq, const float* __restrict__ Wk,
    const float* __restrict__ bq,
    const float* __restrict__ Wv, const float* __restrict__ Wo,
    const float* __restrict__ bv,
    const float* __restrict__ x,  const float* __restrict__ Wc,
    const float* __restrict__ bc,
    short* __restrict__ Wqt, float* __restrict__ bqp,
    short* __restrict__ Wvot, float* __restrict__ bop_part,
    short* __restrict__ x_bf, short* __restrict__ kvc16, short* __restrict__ kvcT)
{
    __shared__ __align__(16) char smem[20736];
    int bid = blockIdx.x, tid = threadIdx.x;
    if (bid < 256) {
        // ---- Wqt + bqp ----
        const float SC = 0.18033688011112042f;  // log2(e)/8
        float (*wk)[64] = (float(*)[64])smem;            // 4096 B
        float (*wq)[65] = (float(*)[65])(smem + 4096);   // 16640 B
        int h = bid >> 4, dt = bid & 15;
        int d0 = dt * 64;
        for (int idx = tid; idx < 1024; idx += 256) {
            int j = idx >> 6, e = idx & 63;
            wk[j][e] = Wk[j*DM + h*HD + e];
        }
        #pragma unroll
        for (int i = 0; i < 16; ++i) {
            int idx = i*256 + tid;
            int r = idx >> 6, e = idx & 63;
            wq[r][e] = Wq[(d0 + r)*DM + h*HD + e];
        }
        __syncthreads();
        int r = tid & 63, j0 = (tid >> 6) * 4;
        float a0=0.f, a1=0.f, a2=0.f, a3=0.f;
        #pragma unroll 8
        for (int e = 0; e < 64; ++e) {
            float a = wq[r][e];
            a0 += a * wk[j0+0][e];
            a1 += a * wk[j0+1][e];
            a2 += a * wk[j0+2][e];
            a3 += a * wk[j0+3][e];
        }
        Wqt[(h*16 + j0+0)*DM + d0 + r] = f2bf(a0 * SC);
        Wqt[(h*16 + j0+1)*DM + d0 + r] = f2bf(a1 * SC);
        Wqt[(h*16 + j0+2)*DM + d0 + r] = f2bf(a2 * SC);
        Wqt[(h*16 + j0+3)*DM + d0 + r] = f2bf(a3 * SC);
        if (dt == 0 && tid < 16) {
            int j = tid;
            float acc = 0.f;
            #pragma unroll 8
            for (int e = 0; e < 64; ++e) acc += bq[h*HD + e] * wk[j][e];
            bqp[h*16 + j] = acc * SC;
        }
    } else if (bid < 320) {
        // ---- Wvot + bop_part ----
        float (*wv)[64] = (float(*)[64])smem;            // 4096 B
        float* bvs = (float*)(smem + 4096);              // 256 B
        int hb = bid - 256;
        int h = hb >> 2, nt = hb & 3;
        int n = nt*256 + tid;
        for (int idx = tid; idx < 1024; idx += 256) {
            int j = idx >> 6, e = idx & 63;
            wv[j][e] = Wv[j*DM + h*HD + e];
        }
        if (tid < 64) bvs[tid] = bv[h*HD + tid];
        __syncthreads();
        float acc[16];
        #pragma unroll
        for (int j = 0; j < 16; ++j) acc[j] = 0.f;
        float bacc = 0.f;
        #pragma unroll 4
        for (int e = 0; e < 64; ++e) {
            float wo = Wo[(h*HD + e)*DM + n];
            bacc += bvs[e] * wo;
            #pragma unroll
            for (int j = 0; j < 16; ++j) acc[j] += wv[j][e] * wo;
        }
        short8 o0, o1;
        #pragma unroll
        for (int j = 0; j < 8; ++j) { o0[j] = f2bf(acc[j]); o1[j] = f2bf(acc[j+8]); }
        *(short8*)(Wvot + n*QP + h*16)     = o0;
        *(short8*)(Wvot + n*QP + h*16 + 8) = o1;
        bop_part[h*DM + n] = bacc;
    } else {
        // ---- x -> bf16, kvc ----
        float (*xs)[DM]      = (float(*)[DM])smem;               // 16384 B
        float (*part)[16][17] = (float(*)[16][17])(smem + 16384); // 4352 B
        int t0 = (bid - 320) * 4;
        #pragma unroll
        for (int i = 0; i < 4; ++i) {
            float4 xv = *(const float4*)(x + (t0+i)*DM + tid*4);
            *(float4*)(&xs[i][tid*4]) = xv;
            short4v xb;
            xb[0]=f2bf(xv.x); xb[1]=f2bf(xv.y); xb[2]=f2bf(xv.z); xb[3]=f2bf(xv.w);
            *(short4v*)(x_bf + (t0+i)*DM + tid*4) = xb;
        }
        __syncthreads();
        int g = tid >> 4, n = tid & 15;
        float a0=0.f, a1=0.f, a2=0.f, a3=0.f;
        #pragma unroll 4
        for (int k = 0; k < 64; ++k) {
            float wc = Wc[(g*64 + k)*KVD + n];
            a0 += xs[0][g*64+k]*wc; a1 += xs[1][g*64+k]*wc;
            a2 += xs[2][g*64+k]*wc; a3 += xs[3][g*64+k]*wc;
        }
        part[0][g][n]=a0; part[1][g][n]=a1; part[2][g][n]=a2; part[3][g][n]=a3;
        __syncthreads();
        if (tid < 64) {
            int i = tid >> 4, nn = tid & 15;
            float s = bc[nn];
            #pragma unroll
            for (int gg = 0; gg < 16; ++gg) s += part[i][gg][nn];
            short v = f2bf(s);
            int t = t0 + i;
            kvc16[t*16 + nn] = v;
            int b = t >> 11, tl = t & (TT-1);
            // tiled V: tile kt = tl>>5, local kv = tl&31 -> half, kv16
            int kt = tl >> 5, kvl = tl & 31;
            int half = kvl >> 4, k16 = kvl & 15;
            int base = ((b*64 + kt)*2 + half) * 512;   // shorts: half-tile = 32x16
            kvcT[base + nn*16 + k16]        = v;
            kvcT[base + (16+nn)*16 + k16]   = (nn == 0) ? (short)0x3F80 : (short)0;
        }
    }
}

// ---------------- fused q'-GEMM + causal latent attention ----------------
// Block = one (b,h,{pp, 63-pp}) pair -> 65 KV-tiles/block (uniform); 1024 blocks
// = 4 blocks/CU; launch_bounds(256,4) -> VGPR cap 128 (round 16's champion body).
// XCD-LOCALITY DECODE (round 18, A/B-verified FETCH 34.6->8.1MB, time-neutral):
// chunk=bid>>7, h=(bid>>3)&15, bp=chunk*8+(bid&7) — with round-robin XCD=bid%8,
// all 16 h-siblings of a (b,pp) pair share one XCD's L2.
// Stage A: 4 waves compute the 64x16 q' pair-tile over full K (32 MFMAs each).
// Stage B (per qt): 4-wave KV split; 2 tiles/iteration with dual accumulators
// (u0/u1); exp fused into cvt_pk pairs; dense 1KB tiled-V loads; denom FREE
// from PV col 16 (ones-row). Stage C: additive combine via ulds.
__global__ __launch_bounds__(256, 4) void attn(
    const short* __restrict__ x_bf, const short* __restrict__ Wqt,
    const float* __restrict__ bqp,
    const short* __restrict__ kvc16, const short* __restrict__ kvcT,
    short* __restrict__ u_bf)
{
    int bid = blockIdx.x;
    int chunk = bid >> 7;                 // 0..7
    int h  = (bid >> 3) & 15;
    int bp = chunk * 8 + (bid & 7);       // 0..63
    int b  = bp >> 5, pp = bp & 31;       // pp in [0,32)
    int tid = threadIdx.x;
    int w = tid >> 6, lane = tid & 63;
    int l15 = lane & 15, g = lane >> 4;
    int l31 = lane & 31, hi = lane >> 5;

    __shared__ __align__(16) char smem[10752];
    short (*qtile)[16]    = (short(*)[16])smem;              // 2048 B [64][16]
    float (*ulds)[32][17] = (float(*)[32][17])(smem + 2048); // 8704 B

    // ---- stage A: wave w computes rows [w*16, w*16+16) of the 64-row pair ----
    {
        int itile = w >> 1, half = w & 1;
        int qb = (itile ? (63 - pp) : pp) * 32 + half * 16;
        f32x4 qa = {0.f,0.f,0.f,0.f};
        const short* ar = x_bf + (b*TT + qb + l15)*DM + 8*g;
        const short* br = Wqt  + (h*16 + l15)*DM + 8*g;
        #pragma unroll 4
        for (int k0 = 0; k0 < DM; k0 += 32) {
            short8 a  = *(const short8*)(ar + k0);
            short8 bb = *(const short8*)(br + k0);
            qa = __builtin_amdgcn_mfma_f32_16x16x32_bf16(a, bb, qa, 0, 0, 0);
        }
        float bias = bqp[h*16 + l15];
        #pragma unroll
        for (int r = 0; r < 4; ++r)
            qtile[w*16 + 4*g + r][l15] = f2bf(qa[r] + bias);   // row=q, col=lat
    }
    __syncthreads();

    const short* kbase = kvc16 + (b*TT + l31)*16 + 8*hi;
    const short* vbase = kvcT + b*65536 + l31*16 + 8*hi;   // + kt*1024 (+512 for vb)

    #pragma unroll 1
    for (int it = 0; it < 2; ++it) {
        int qt = it ? (63 - pp) : pp;
        int qbase = qt * 32;
        short8 qf = *(const short8*)(&qtile[it*32 + l31][8*hi]);   // B-frag: j=q, k=lat

        int ntiles = qt + 1;
        int t0 = (w * ntiles) >> 2;
        int t1 = ((w + 1) * ntiles) >> 2;

        f32x16 u0, u1, zf;
        #pragma unroll
        for (int r = 0; r < 16; ++r) { u0[r] = 0.f; u1[r] = 0.f; zf[r] = 0.f; }

        int kt = t0;
        // ---- 2 tiles per iteration: independent chains, dual accumulators ----
        for (; kt + 2 <= t1; kt += 2) {
            short8 kf0 = *(const short8*)(kbase + (kt << 9));
            short8 kf1 = *(const short8*)(kbase + ((kt + 1) << 9));
            const short* v0 = vbase + (kt << 10);
            short8 va0 = *(const short8*)(v0);
            short8 vb0 = *(const short8*)(v0 + 512);
            short8 va1 = *(const short8*)(v0 + 1024);
            short8 vb1 = *(const short8*)(v0 + 1536);
            f32x16 st0 = __builtin_amdgcn_mfma_f32_32x32x16_bf16(kf0, qf, zf, 0, 0, 0);
            f32x16 st1 = __builtin_amdgcn_mfma_f32_32x32x16_bf16(kf1, qf, zf, 0, 0, 0);
            if (kt + 1 == qt) {                  // diagonal can only be the last tile
                #pragma unroll
                for (int r = 0; r < 16; ++r) {
                    int kvl = (r & 3) + 8*(r >> 2) + 4*hi;
                    if (kvl > l31) st1[r] = -INFINITY;
                }
            }
            int wd[16];
            #pragma unroll
            for (int i = 0; i < 8; ++i) {        // exp fused into pack pairs
                float pa = fexp2(st0[2*i]), pb = fexp2(st0[2*i+1]);
                asm("v_cvt_pk_bf16_f32 %0, %1, %2" : "=v"(wd[i]) : "v"(pa), "v"(pb));
                float pc = fexp2(st1[2*i]), pd = fexp2(st1[2*i+1]);
                asm("v_cvt_pk_bf16_f32 %0, %1, %2" : "=v"(wd[8+i]) : "v"(pc), "v"(pd));
            }
            int c00 = wd[0],  c02 = wd[2],  c01 = wd[1],  c03 = wd[3];
            int c10 = wd[4],  c12 = wd[6],  c11 = wd[5],  c13 = wd[7];
            int d00 = wd[8],  d02 = wd[10], d01 = wd[9],  d03 = wd[11];
            int d10 = wd[12], d12 = wd[14], d11 = wd[13], d13 = wd[15];
            asm volatile("v_permlane32_swap_b32 %0, %1" : "+v"(c00), "+v"(c02));
            asm volatile("v_permlane32_swap_b32 %0, %1" : "+v"(c01), "+v"(c03));
            asm volatile("v_permlane32_swap_b32 %0, %1" : "+v"(c10), "+v"(c12));
            asm volatile("v_permlane32_swap_b32 %0, %1" : "+v"(c11), "+v"(c13));
            asm volatile("v_permlane32_swap_b32 %0, %1" : "+v"(d00), "+v"(d02));
            asm volatile("v_permlane32_swap_b32 %0, %1" : "+v"(d01), "+v"(d03));
            asm volatile("v_permlane32_swap_b32 %0, %1" : "+v"(d10), "+v"(d12));
            asm volatile("v_permlane32_swap_b32 %0, %1" : "+v"(d11), "+v"(d13));
            union { int i4[4]; short8 s8; } pa0, pa1, pb0, pb1;
            pa0.i4[0]=c00; pa0.i4[1]=c01; pa0.i4[2]=c02; pa0.i4[3]=c03;
            pa1.i4[0]=c10; pa1.i4[1]=c11; pa1.i4[2]=c12; pa1.i4[3]=c13;
            pb0.i4[0]=d00; pb0.i4[1]=d01; pb0.i4[2]=d02; pb0.i4[3]=d03;
            pb1.i4[0]=d10; pb1.i4[1]=d11; pb1.i4[2]=d12; pb1.i4[3]=d13;
            u0 = __builtin_amdgcn_mfma_f32_32x32x16_bf16(pa0.s8, va0, u0, 0, 0, 0);
            u1 = __builtin_amdgcn_mfma_f32_32x32x16_bf16(pb0.s8, va1, u1, 0, 0, 0);
            u0 = __builtin_amdgcn_mfma_f32_32x32x16_bf16(pa1.s8, vb0, u0, 0, 0, 0);
            u1 = __builtin_amdgcn_mfma_f32_32x32x16_bf16(pb1.s8, vb1, u1, 0, 0, 0);
        }
        // ---- tail: single tile (possibly diagonal) ----
        if (kt < t1) {
            short8 kf = *(const short8*)(kbase + (kt << 9));
            const short* v0 = vbase + (kt << 10);
            short8 va = *(const short8*)(v0);
            short8 vb = *(const short8*)(v0 + 512);
            f32x16 st = __builtin_amdgcn_mfma_f32_32x32x16_bf16(kf, qf, zf, 0, 0, 0);
            if (kt == qt) {
                #pragma unroll
                for (int r = 0; r < 16; ++r) {
                    int kvl = (r & 3) + 8*(r >> 2) + 4*hi;
                    if (kvl > l31) st[r] = -INFINITY;
                }
            }
            int wd[8];
            #pragma unroll
            for (int i = 0; i < 8; ++i) {
                float pa = fexp2(st[2*i]), pb = fexp2(st[2*i+1]);
                asm("v_cvt_pk_bf16_f32 %0, %1, %2" : "=v"(wd[i]) : "v"(pa), "v"(pb));
            }
            int c00 = wd[0], c02 = wd[2], c01 = wd[1], c03 = wd[3];
            int c10 = wd[4], c12 = wd[6], c11 = wd[5], c13 = wd[7];
            asm volatile("v_permlane32_swap_b32 %0, %1" : "+v"(c00), "+v"(c02));
            asm volatile("v_permlane32_swap_b32 %0, %1" : "+v"(c01), "+v"(c03));
            asm volatile("v_permlane32_swap_b32 %0, %1" : "+v"(c10), "+v"(c12));
            asm volatile("v_permlane32_swap_b32 %0, %1" : "+v"(c11), "+v"(c13));
            union { int i4[4]; short8 s8; } pa0, pa1;
            pa0.i4[0]=c00; pa0.i4[1]=c01; pa0.i4[2]=c02; pa0.i4[3]=c03;
            pa1.i4[0]=c10; pa1.i4[1]=c11; pa1.i4[2]=c12; pa1.i4[3]=c13;
            u0 = __builtin_amdgcn_mfma_f32_32x32x16_bf16(pa0.s8, va, u0, 0, 0, 0);
            u0 = __builtin_amdgcn_mfma_f32_32x32x16_bf16(pa1.s8, vb, u0, 0, 0, 0);
        }
        #pragma unroll
        for (int r = 0; r < 16; ++r) u0[r] += u1[r];

        // ---- stage C: combine (partials additive; col 16 = denominator) ----
        #pragma unroll
        for (int r = 0; r < 16; ++r) {
            int q = (r & 3) + 8*(r >> 2) + 4*hi;
            if (l31 < 17) ulds[w][q][l31] = u0[r];
        }
        __syncthreads();
        #pragma unroll
        for (int e = 0; e < 2; ++e) {
            int idx = tid*2 + e;
            int q = idx >> 4, lat = idx & 15;
            float us = ulds[0][q][lat] + ulds[1][q][lat] + ulds[2][q][lat] + ulds[3][q][lat];
            float dd = ulds[0][q][16]  + ulds[1][q][16]  + ulds[2][q][16]  + ulds[3][q][16];
            u_bf[(b*TT + qbase + q)*QP + h*16 + lat] = f2bf(us / dd);
        }
        __syncthreads();   // ulds reuse safety before next it
    }
}

// ---------------- output GEMM: out = U @ Wvo + (bo + bv@Wo) ----------------
__global__ __launch_bounds__(256) void ogemm(
    const short* __restrict__ u_bf, const short* __restrict__ Wvot,
    const float* __restrict__ bo, const float* __restrict__ bop_part,
    float* __restrict__ out)
{
    int bid = blockIdx.x;
    int w = threadIdx.x >> 6, lane = threadIdx.x & 63;
    int l15 = lane & 15, g = lane >> 4;
    int m0 = (bid >> 4)*64 + w*16;
    int nb = (bid & 15)*64;
    __shared__ float bs[64];
    int tid = threadIdx.x;
    if (tid < 64) {
        int n = nb + tid;
        float s = bo[n];
        #pragma unroll
        for (int hh = 0; hh < 16; ++hh) s += bop_part[hh*DM + n];
        bs[tid] = s;
    }
    __syncthreads();
    f32x4 acc[4];
    #pragma unroll
    for (int nt = 0; nt < 4; ++nt) acc[nt] = (f32x4){0.f,0.f,0.f,0.f};
    const short* arow = u_bf + (m0 + l15)*QP + 8*g;
    for (int k0 = 0; k0 < QP; k0 += 32) {
        short8 a = *(const short8*)(arow + k0);
        #pragma unroll
        for (int nt = 0; nt < 4; ++nt) {
            short8 bfr = *(const short8*)(Wvot + (nb + nt*16 + l15)*QP + k0 + 8*g);
            acc[nt] = __builtin_amdgcn_mfma_f32_16x16x32_bf16(a, bfr, acc[nt], 0, 0, 0);
        }
    }
    #pragma unroll
    for (int nt = 0; nt < 4; ++nt) {
        int n = nb + nt*16 + l15;
        float bias = bs[nt*16 + l15];
        #pragma unroll
        for (int r = 0; r < 4; ++r)
            out[(m0 + 4*g + r)*DM + n] = acc[nt][r] + bias;
    }
}

extern "C" void kernel_launch(void* const* d_in, const int* in_sizes, int n_in,
                              void* d_out, int out_size, void* d_ws, size_t ws_size,
                              hipStream_t stream) {
    const float* x  = (const float*)d_in[0];
    const float* Wc = (const float*)d_in[1];
    const float* bc = (const float*)d_in[2];
    const float* Wk = (const float*)d_in[3];
    // d_in[4] = bk: drops out of softmax (constant per row)
    const float* Wv = (const float*)d_in[5];
    const float* bv = (const float*)d_in[6];
    const float* Wq = (const float*)d_in[7];
    const float* bq = (const float*)d_in[8];
    const float* Wo = (const float*)d_in[9];
    const float* bo = (const float*)d_in[10];
    // d_in[11] = mask: causal, implemented directly
    float* out = (float*)d_out;

    char* ws = (char*)d_ws;                       // needs 16 MiB
    short* x_bf     = (short*)(ws);                              // 8 MiB
    short* Wqt      = (short*)(ws + (8u<<20));                   // 512 KiB
    short* Wvot     = (short*)(ws + (8u<<20) + (512u<<10));      // 512 KiB
    float* bqp      = (float*)(ws + (9u<<20));                   // 1 KiB
    float* bop_part = (float*)(ws + (9u<<20) + 8192);            // 64 KiB
    short* kvc16    = (short*)(ws + (9u<<20) + (512u<<10));      // 128 KiB
    short* kvcT     = (short*)(ws + (9u<<20) + (768u<<10));      // 256 KiB tiled [b][kt][half][32][16]
    short* u_bf     = (short*)(ws + (14u<<20));                  // 2 MiB

    hipLaunchKernelGGL(prep_all, dim3(1344), dim3(256), 0, stream,
                       Wq, Wk, bq, Wv, Wo, bv, x, Wc, bc,
                       Wqt, bqp, Wvot, bop_part, x_bf, kvc16, kvcT);
    hipLaunchKernelGGL(attn,     dim3(1024), dim3(256), 0, stream,
                       x_bf, Wqt, bqp, kvc16, kvcT, u_bf);
    hipLaunchKernelGGL(ogemm,    dim3(1024), dim3(256), 0, stream,
                       u_bf, Wvot, bo, bop_part, out);
}